// Round 22
// baseline (133.590 us; speedup 1.0000x reference)
//
#include <hip/hip_runtime.h>
#include <hip/hip_bf16.h>
#include <stdint.h>

// Problem constants
constexpr int cB = 2;
constexpr int cS = 2048;
constexpr int cH = 1024;
constexpr int cNH = 16;
constexpr int cHD = 64;
constexpr int cBS = cB * cS;  // 4096

typedef short short8 __attribute__((ext_vector_type(8)));
typedef short short4v __attribute__((ext_vector_type(4)));
typedef float f32x4 __attribute__((ext_vector_type(4)));
typedef unsigned short us4 __attribute__((ext_vector_type(4)));
typedef unsigned uint4v __attribute__((ext_vector_type(4)));

constexpr float LOG2E = 1.4426950408889634f;

// HW bf16 convert (RNE)
__device__ inline unsigned short f2bf(float f) {
  __hip_bfloat16 h = __float2bfloat16(f);
  return __builtin_bit_cast(unsigned short, h);
}

// Bare v_exp_f32 (2^x) — r17-verified.
__device__ inline float fexp2(float x) {
#if __has_builtin(__builtin_amdgcn_exp2f)
  return __builtin_amdgcn_exp2f(x);
#else
  return __expf(x * 0.6931471805599453f);
#endif
}

__device__ inline void gload_lds16(const void* g, void* l) {
  __builtin_amdgcn_global_load_lds(
      (const __attribute__((address_space(1))) void*)g,
      (__attribute__((address_space(3))) void*)l,
      16, 0, 0);
}

// ds_read_b64_tr_b16 (verified r7)
__device__ inline short4v tr16(const unsigned short* p) {
  short4v d;
  auto p3 = (const __attribute__((address_space(3))) unsigned short*)p;
  asm volatile("ds_read_b64_tr_b16 %0, %1" : "=v"(d) : "v"(p3) : "memory");
  return d;
}

// permlane32 swap (r21-verified in-kernel): a' = [a(0-31)|b(0-31)],
// b' = [a(32-63)|b(32-63)].
__device__ inline void swap32(unsigned& a, unsigned& b) {
  asm("v_permlane32_swap_b32 %0, %1" : "+v"(a), "+v"(b));
}

// ---------------- fp32 -> bf16 convert ----------------
__global__ void cvt_f32_bf16(const float* __restrict__ src,
                             unsigned short* __restrict__ dst, int n) {
  int i = (blockIdx.x * blockDim.x + threadIdx.x) * 4;
  if (i >= n) return;
  f32x4 v = *reinterpret_cast<const f32x4*>(src + i);
  us4 o = {f2bf(v[0]), f2bf(v[1]), f2bf(v[2]), f2bf(v[3])};
  *reinterpret_cast<us4*>(dst + i) = o;
}

// ---------------- QKV GEMM (r17/r20, green) ----------------
constexpr int BM = 128, BN = 128, BK = 32;

__global__ __launch_bounds__(256) void qkv_gemm(
    const unsigned short* __restrict__ Xb,  // [4096][1024] bf16
    const unsigned short* __restrict__ Wqb, // [1024][1024] bf16
    const unsigned short* __restrict__ Wkb,
    const unsigned short* __restrict__ Wvb,
    const float* __restrict__ bq, const float* __restrict__ bk,
    const float* __restrict__ bv,
    unsigned short* __restrict__ Qb, unsigned short* __restrict__ Kb,
    unsigned short* __restrict__ Vb) {
  __shared__ alignas(16) unsigned short As[BM * BK];  // 8 KB
  __shared__ alignas(16) unsigned short Bs[BN * BK];

  const int nb = blockIdx.x;  // 0..23
  const int mb = blockIdx.y;  // 0..31
  const int m0 = mb * BM;
  const int wsel = nb >> 3;
  const int n0 = (nb & 7) * BN;
  const unsigned short* W = (wsel == 0) ? Wqb : (wsel == 1 ? Wkb : Wvb);
  const float* bias = (wsel == 0) ? bq : (wsel == 1 ? bk : bv);
  unsigned short* Out = (wsel == 0) ? Qb : (wsel == 1 ? Kb : Vb);
  const float oscale = (wsel == 0) ? 0.125f * LOG2E : 1.0f;

  const int t = threadIdx.x;
  const int w = t >> 6, l = t & 63, lr = l & 15, lg = l >> 4;
  const int wm = w >> 1, wn = w & 1;

  f32x4 acc[4][4];
#pragma unroll
  for (int mi = 0; mi < 4; ++mi)
#pragma unroll
    for (int ni = 0; ni < 4; ++ni) acc[mi][ni] = {0.f, 0.f, 0.f, 0.f};

  const int tb = t * 16;

  for (int kt = 0; kt < cH / BK; ++kt) {
    const int k0 = kt * BK;
    __syncthreads();
#pragma unroll
    for (int s = 0; s < 2; ++s) {
      const int ib = s * 4096 + tb;
      const int row = ib >> 6;
      const int cole = (ib & 63) >> 1;
      gload_lds16(Xb + (size_t)(m0 + row) * cH + k0 + cole,
                  ((char*)As) + s * 4096 + w * 1024);
      gload_lds16(W + (size_t)(n0 + row) * cH + k0 + cole,
                  ((char*)Bs) + s * 4096 + w * 1024);
    }
    asm volatile("s_waitcnt vmcnt(0)" ::: "memory");
    __syncthreads();

    short8 af[4], bfr[4];
#pragma unroll
    for (int mi = 0; mi < 4; ++mi)
      af[mi] = *reinterpret_cast<const short8*>(
          &As[(wm * 64 + mi * 16 + lr) * BK + lg * 8]);
#pragma unroll
    for (int ni = 0; ni < 4; ++ni)
      bfr[ni] = *reinterpret_cast<const short8*>(
          &Bs[(wn * 64 + ni * 16 + lr) * BK + lg * 8]);
#pragma unroll
    for (int mi = 0; mi < 4; ++mi)
#pragma unroll
      for (int ni = 0; ni < 4; ++ni)
        acc[mi][ni] = __builtin_amdgcn_mfma_f32_16x16x32_bf16(
            af[mi], bfr[ni], acc[mi][ni], 0, 0, 0);
  }

#pragma unroll
  for (int ni = 0; ni < 4; ++ni) {
    const int col = n0 + wn * 64 + ni * 16 + lr;
    const float bvv = bias[col];
#pragma unroll
    for (int mi = 0; mi < 4; ++mi) {
      const int row = m0 + wm * 64 + mi * 16 + lg * 4;
#pragma unroll
      for (int r = 0; r < 4; ++r)
        Out[(size_t)(row + r) * cH + col] =
            f2bf((acc[mi][ni][r] + bvv) * oscale);
    }
  }
}

// ---------------- Flash attention ----------------
// r21 in-register-P structure; r22: block = 2 waves x 64 q-rows
// (grid 32x32 = 1024 blocks = 4 independent barrier-groups/CU, was 2).
// Latency-bound kernel (no pipe >50%) -> more independent groups to overlap.
__global__ __launch_bounds__(128) void attn_kernel(
    const unsigned short* __restrict__ Qb,  // [B*S][H] bf16 (pre-scaled)
    const unsigned short* __restrict__ Kb,
    const unsigned short* __restrict__ Vb,
    const float* __restrict__ mask,         // [B][S]
    float* __restrict__ out) {              // [B*S][H] fp32
  __shared__ alignas(16) unsigned short Ks[2][64 * 64];  // 16 KB
  __shared__ alignas(16) unsigned short Vs[2][64 * 64];  // 16 KB

  const int qb = blockIdx.x;  // 0..31
  const int bh = blockIdx.y;  // 0..31
  const int b = bh >> 4, h = bh & 15;
  const int t = threadIdx.x;
  const int w = t >> 6, l = t & 63, lr = l & 15, lg = l >> 4;  // w in 0..1
  const int q0 = qb * 64 + w * 32;

  const unsigned short* Kbase = Kb + (size_t)b * cS * cH + h * cHD;
  const unsigned short* Vbase = Vb + (size_t)b * cS * cH + h * cHD;
  const float* mbase = mask + b * cS;

  // routing selectors (precomputed)
  const int sel = (l >> 4) & 1;       // 1 for lanes 16-31, 48-63
  const int idxm16 = l - 16;          // used by sel lanes
  const int idxp16 = (l + 16) & 63;   // used by !sel lanes

  // Staging decode (r7-verified formulas): wave w owns shots 4w..4w+3.
  int rK[4], cK[4], rV[4], cV[4];
#pragma unroll
  for (int s2 = 0; s2 < 4; ++s2) {
    const int g = (w * 4 + s2) * 64 + l;
    const int gr = g >> 3, gc = g & 7;
    rK[s2] = gr;
    cK[s2] = (gc ^ (gr & 7)) * 8;
    rV[s2] = (gr >> 2) * 4 + (gc >> 1);
    cV[s2] = (gr & 3) * 16 + (gc & 1) * 8;
  }

  // Q fragments for 2 subtiles (q=lr rows; B-operand after swap)
  short8 qf[2][2];
#pragma unroll
  for (int qi = 0; qi < 2; ++qi) {
    const unsigned short* Qrow =
        Qb + (size_t)(b * cS + q0 + qi * 16 + lr) * cH + h * cHD;
    qf[qi][0] = *reinterpret_cast<const short8*>(Qrow + lg * 8);
    qf[qi][1] = *reinterpret_cast<const short8*>(Qrow + 32 + lg * 8);
  }

  short8 ones;
#pragma unroll
  for (int j = 0; j < 8; ++j) ones[j] = (short)0x3F80;

  f32x4 oacc[2][4];
  f32x4 osum[2];
  float mrow[2];  // per-lane running max for q = lr
#pragma unroll
  for (int qi = 0; qi < 2; ++qi) {
    osum[qi] = {0.f, 0.f, 0.f, 0.f};
#pragma unroll
    for (int d16 = 0; d16 < 4; ++d16) oacc[qi][d16] = {0.f, 0.f, 0.f, 0.f};
    mrow[qi] = -1e30f;
  }

  auto stage = [&](int bufi, int kv0) {
#pragma unroll
    for (int s2 = 0; s2 < 4; ++s2) {
      gload_lds16(Kbase + (size_t)(kv0 + rK[s2]) * cH + cK[s2],
                  (char*)&Ks[bufi][0] + (w * 4 + s2) * 1024);
      gload_lds16(Vbase + (size_t)(kv0 + rV[s2]) * cH + cV[s2],
                  (char*)&Vs[bufi][0] + (w * 4 + s2) * 1024);
    }
  };

  stage(0, 0);
  asm volatile("s_waitcnt vmcnt(0)" ::: "memory");
  __syncthreads();

  constexpr int NT = cS / 64;  // 32
  for (int kt = 0; kt < NT; ++kt) {
    const int bufi = kt & 1;
    if (kt + 1 < NT) stage(bufi ^ 1, (kt + 1) * 64);

    const unsigned short* Kt = &Ks[bufi][0];
    const unsigned short* Vt = &Vs[bufi][0];
    const int kv0 = kt * 64;

    // ---- load ALL K fragments (A-operand rows k=n*16+lr) ----
    short8 kfs[4][2];
#pragma unroll
    for (int n = 0; n < 4; ++n) {
      const int kr = n * 16 + lr;
      const unsigned sw = (unsigned)((kr & 7) << 4);
      const unsigned b0 = ((unsigned)(kr * 128 + lg * 16)) ^ sw;
      const unsigned b1 = ((unsigned)(kr * 128 + 64 + lg * 16)) ^ sw;
      kfs[n][0] = *reinterpret_cast<const short8*>((const char*)Kt + b0);
      kfs[n][1] = *reinterpret_cast<const short8*>((const char*)Kt + b1);
    }

    // ---- issue ALL V tr16 EARLY (latency hidden under QK^T+softmax) ----
    short4v tv[2][8];
#pragma unroll
    for (int ks2 = 0; ks2 < 2; ++ks2)
#pragma unroll
      for (int d16 = 0; d16 < 4; ++d16) {
        const unsigned short* a0 =
            Vt + (ks2 * 8 + lg * 2) * 256 + d16 * 64 + lr * 4;
        tv[ks2][2 * d16] = tr16(a0);
        tv[ks2][2 * d16 + 1] = tr16(a0 + 256);
      }

    // ---- mask (k = n*16 + lg*4 + r), log2e-scaled ----
    f32x4 maskv[4];
#pragma unroll
    for (int n = 0; n < 4; ++n) {
      f32x4 m = *reinterpret_cast<const f32x4*>(&mbase[kv0 + n * 16 + lg * 4]);
#pragma unroll
      for (int r = 0; r < 4; ++r) m[r] *= LOG2E;
      maskv[n] = m;
    }

    // ---- swapped QK^T: sc[qi][n][r] = S[k=n*16+lg*4+r][q=lr] + mask[k] ----
    f32x4 sc[2][4];
#pragma unroll
    for (int n = 0; n < 4; ++n)
#pragma unroll
      for (int qi = 0; qi < 2; ++qi) {
        f32x4 z = {0.f, 0.f, 0.f, 0.f};
        z = __builtin_amdgcn_mfma_f32_16x16x32_bf16(kfs[n][0], qf[qi][0], z, 0, 0, 0);
        z = __builtin_amdgcn_mfma_f32_16x16x32_bf16(kfs[n][1], qf[qi][1], z, 0, 0, 0);
        sc[qi][n] = z + maskv[n];
      }

    // ---- softmax max: local 16-tree + shfl_xor(16,32) cross-lg reduce ----
    float mnew[2];
    int ok = 1;
#pragma unroll
    for (int qi = 0; qi < 2; ++qi) {
      float a0 = fmaxf(fmaxf(sc[qi][0][0], sc[qi][0][1]),
                       fmaxf(sc[qi][0][2], sc[qi][0][3]));
      float a1 = fmaxf(fmaxf(sc[qi][1][0], sc[qi][1][1]),
                       fmaxf(sc[qi][1][2], sc[qi][1][3]));
      float a2 = fmaxf(fmaxf(sc[qi][2][0], sc[qi][2][1]),
                       fmaxf(sc[qi][2][2], sc[qi][2][3]));
      float a3 = fmaxf(fmaxf(sc[qi][3][0], sc[qi][3][1]),
                       fmaxf(sc[qi][3][2], sc[qi][3][3]));
      float mx = fmaxf(fmaxf(a0, a1), fmaxf(a2, a3));
      mx = fmaxf(mx, __shfl_xor(mx, 16));
      mx = fmaxf(mx, __shfl_xor(mx, 32));
      mnew[qi] = fmaxf(mrow[qi], mx);
      ok &= (mx - mrow[qi] <= 11.5416f) ? 1 : 0;
    }
    if (!__all(ok)) {
#pragma unroll
      for (int qi = 0; qi < 2; ++qi) {
        const float dlt = mrow[qi] - mnew[qi];  // <= 0, per q=lr
        mrow[qi] = mnew[qi];
#pragma unroll
        for (int r = 0; r < 4; ++r) {
          // oacc/osum row r is q = lg*4+r -> delta from lane (lg*4+r)
          const float s = fexp2(__shfl(dlt, lg * 4 + r));
          osum[qi][r] *= s;
#pragma unroll
          for (int d16 = 0; d16 < 4; ++d16) oacc[qi][d16][r] *= s;
        }
      }
    }

    // ---- P = exp2(sc - mrow), bf16-pack into dwords per block n ----
    unsigned d0[2][4], d1[2][4];
#pragma unroll
    for (int qi = 0; qi < 2; ++qi)
#pragma unroll
      for (int n = 0; n < 4; ++n) {
        const float p0 = fexp2(sc[qi][n][0] - mrow[qi]);
        const float p1 = fexp2(sc[qi][n][1] - mrow[qi]);
        const float p2 = fexp2(sc[qi][n][2] - mrow[qi]);
        const float p3 = fexp2(sc[qi][n][3] - mrow[qi]);
        d0[qi][n] = (unsigned)f2bf(p0) | ((unsigned)f2bf(p1) << 16);
        d1[qi][n] = (unsigned)f2bf(p2) | ((unsigned)f2bf(p3) << 16);
      }

    // ---- drain V reads; PV with swap32+shfl routed pa ----
    asm volatile("s_waitcnt lgkmcnt(0)" ::: "memory");
    __builtin_amdgcn_sched_barrier(0);
#pragma unroll
    for (int ks2 = 0; ks2 < 2; ++ks2) {
      const int a = ks2 * 2;
      short8 pa[2];
#pragma unroll
      for (int qi = 0; qi < 2; ++qi) {
        unsigned A0 = d0[qi][a], B0 = d0[qi][a + 1];
        unsigned A1 = d1[qi][a], B1 = d1[qi][a + 1];
        swap32(A0, B0);  // A0=[X0-31|Y0-31], B0=[X32-63|Y32-63]
        swap32(A1, B1);
        const unsigned sB0 = (unsigned)__shfl((int)B0, idxm16);
        const unsigned sA0 = (unsigned)__shfl((int)A0, idxp16);
        const unsigned sB1 = (unsigned)__shfl((int)B1, idxm16);
        const unsigned sA1 = (unsigned)__shfl((int)A1, idxp16);
        const unsigned j01 = sel ? sB0 : A0;
        const unsigned j45 = sel ? B0 : sA0;
        const unsigned j23 = sel ? sB1 : A1;
        const unsigned j67 = sel ? B1 : sA1;
        uint4v q4 = {j01, j23, j45, j67};
        pa[qi] = __builtin_bit_cast(short8, q4);
      }
      osum[0] = __builtin_amdgcn_mfma_f32_16x16x32_bf16(pa[0], ones, osum[0],
                                                        0, 0, 0);
      osum[1] = __builtin_amdgcn_mfma_f32_16x16x32_bf16(pa[1], ones, osum[1],
                                                        0, 0, 0);
#pragma unroll
      for (int d16 = 0; d16 < 4; ++d16) {
        short8 vf;
#pragma unroll
        for (int j = 0; j < 4; ++j) {
          vf[j] = tv[ks2][2 * d16][j];
          vf[4 + j] = tv[ks2][2 * d16 + 1][j];
        }
        oacc[0][d16] = __builtin_amdgcn_mfma_f32_16x16x32_bf16(
            pa[0], vf, oacc[0][d16], 0, 0, 0);
        oacc[1][d16] = __builtin_amdgcn_mfma_f32_16x16x32_bf16(
            pa[1], vf, oacc[1][d16], 0, 0, 0);
      }
    }

    asm volatile("s_waitcnt vmcnt(0)" ::: "memory");
    __syncthreads();  // staged tile kt+1 ready; all waves done with buf kt
  }

  // fp32 store; denominator from the MFMA row-sum accumulator
#pragma unroll
  for (int qi = 0; qi < 2; ++qi) {
    float* obase =
        out + (size_t)(b * cS + q0 + qi * 16 + lg * 4) * cH + h * cHD;
#pragma unroll
    for (int r = 0; r < 4; ++r) {
      const float inv = 1.0f / osum[qi][r];
#pragma unroll
      for (int d16 = 0; d16 < 4; ++d16)
        obase[(size_t)r * cH + d16 * 16 + lr] = oacc[qi][d16][r] * inv;
    }
  }
}

// ---------------- launcher ----------------
extern "C" void kernel_launch(void* const* d_in, const int* in_sizes, int n_in,
                              void* d_out, int out_size, void* d_ws,
                              size_t ws_size, hipStream_t stream) {
  const float* X = (const float*)d_in[0];     // [B,S,H]
  const float* mask = (const float*)d_in[1];  // [B,1,1,S]
  const float* Wq = (const float*)d_in[2];
  const float* bq = (const float*)d_in[3];
  const float* Wk = (const float*)d_in[4];
  const float* bk = (const float*)d_in[5];
  const float* Wv = (const float*)d_in[6];
  const float* bv = (const float*)d_in[7];
  float* outp = (float*)d_out;  // fp32 (reference output dtype)

  // workspace (38 MB; established safe):
  char* ws = (char*)d_ws;
  const size_t MB = 1 << 20;
  unsigned short* Xb  = (unsigned short*)(ws + 0 * MB);   // 8 MB
  unsigned short* Wqb = (unsigned short*)(ws + 8 * MB);   // 2 MB
  unsigned short* Wkb = (unsigned short*)(ws + 10 * MB);  // 2 MB
  unsigned short* Wvb = (unsigned short*)(ws + 12 * MB);  // 2 MB
  unsigned short* Qb  = (unsigned short*)(ws + 14 * MB);  // 8 MB
  unsigned short* Kb  = (unsigned short*)(ws + 22 * MB);  // 8 MB
  unsigned short* Vb  = (unsigned short*)(ws + 30 * MB);  // 8 MB

  cvt_f32_bf16<<<cBS * cH / 1024, 256, 0, stream>>>(X, Xb, cBS * cH);
  cvt_f32_bf16<<<cH * cH / 1024, 256, 0, stream>>>(Wq, Wqb, cH * cH);
  cvt_f32_bf16<<<cH * cH / 1024, 256, 0, stream>>>(Wk, Wkb, cH * cH);
  cvt_f32_bf16<<<cH * cH / 1024, 256, 0, stream>>>(Wv, Wvb, cH * cH);

  qkv_gemm<<<dim3(24, 32), 256, 0, stream>>>(Xb, Wqb, Wkb, Wvb, bq, bk, bv,
                                             Qb, Kb, Vb);
  attn_kernel<<<dim3(32, 32), 128, 0, stream>>>(Qb, Kb, Vb, mask, outp);
}

// Round 23
// 126.604 us; speedup vs baseline: 1.0552x; 1.0552x over previous
//
#include <hip/hip_runtime.h>
#include <hip/hip_bf16.h>
#include <stdint.h>

// Problem constants
constexpr int cB = 2;
constexpr int cS = 2048;
constexpr int cH = 1024;
constexpr int cNH = 16;
constexpr int cHD = 64;
constexpr int cBS = cB * cS;  // 4096

typedef short short8 __attribute__((ext_vector_type(8)));
typedef short short4v __attribute__((ext_vector_type(4)));
typedef float f32x4 __attribute__((ext_vector_type(4)));
typedef unsigned short us4 __attribute__((ext_vector_type(4)));
typedef unsigned uint4v __attribute__((ext_vector_type(4)));

constexpr float LOG2E = 1.4426950408889634f;

// HW bf16 convert (RNE)
__device__ inline unsigned short f2bf(float f) {
  __hip_bfloat16 h = __float2bfloat16(f);
  return __builtin_bit_cast(unsigned short, h);
}

// Bare v_exp_f32 (2^x) — r17-verified.
__device__ inline float fexp2(float x) {
#if __has_builtin(__builtin_amdgcn_exp2f)
  return __builtin_amdgcn_exp2f(x);
#else
  return __expf(x * 0.6931471805599453f);
#endif
}

__device__ inline void gload_lds16(const void* g, void* l) {
  __builtin_amdgcn_global_load_lds(
      (const __attribute__((address_space(1))) void*)g,
      (__attribute__((address_space(3))) void*)l,
      16, 0, 0);
}

// ds_read_b64_tr_b16 (verified r7)
__device__ inline short4v tr16(const unsigned short* p) {
  short4v d;
  auto p3 = (const __attribute__((address_space(3))) unsigned short*)p;
  asm volatile("ds_read_b64_tr_b16 %0, %1" : "=v"(d) : "v"(p3) : "memory");
  return d;
}

// permlane32 swap (r21-verified in-kernel): a' = [a(0-31)|b(0-31)],
// b' = [a(32-63)|b(32-63)].
__device__ inline void swap32(unsigned& a, unsigned& b) {
  asm("v_permlane32_swap_b32 %0, %1" : "+v"(a), "+v"(b));
}

// ---------------- fp32 -> bf16 convert ----------------
__global__ void cvt_f32_bf16(const float* __restrict__ src,
                             unsigned short* __restrict__ dst, int n) {
  int i = (blockIdx.x * blockDim.x + threadIdx.x) * 4;
  if (i >= n) return;
  f32x4 v = *reinterpret_cast<const f32x4*>(src + i);
  us4 o = {f2bf(v[0]), f2bf(v[1]), f2bf(v[2]), f2bf(v[3])};
  *reinterpret_cast<us4*>(dst + i) = o;
}

// ---------------- QKV GEMM (r17/r20, green) ----------------
constexpr int BM = 128, BN = 128, BK = 32;

__global__ __launch_bounds__(256) void qkv_gemm(
    const unsigned short* __restrict__ Xb,  // [4096][1024] bf16
    const unsigned short* __restrict__ Wqb, // [1024][1024] bf16
    const unsigned short* __restrict__ Wkb,
    const unsigned short* __restrict__ Wvb,
    const float* __restrict__ bq, const float* __restrict__ bk,
    const float* __restrict__ bv,
    unsigned short* __restrict__ Qb, unsigned short* __restrict__ Kb,
    unsigned short* __restrict__ Vb) {
  __shared__ alignas(16) unsigned short As[BM * BK];  // 8 KB
  __shared__ alignas(16) unsigned short Bs[BN * BK];

  const int nb = blockIdx.x;  // 0..23
  const int mb = blockIdx.y;  // 0..31
  const int m0 = mb * BM;
  const int wsel = nb >> 3;
  const int n0 = (nb & 7) * BN;
  const unsigned short* W = (wsel == 0) ? Wqb : (wsel == 1 ? Wkb : Wvb);
  const float* bias = (wsel == 0) ? bq : (wsel == 1 ? bk : bv);
  unsigned short* Out = (wsel == 0) ? Qb : (wsel == 1 ? Kb : Vb);
  const float oscale = (wsel == 0) ? 0.125f * LOG2E : 1.0f;

  const int t = threadIdx.x;
  const int w = t >> 6, l = t & 63, lr = l & 15, lg = l >> 4;
  const int wm = w >> 1, wn = w & 1;

  f32x4 acc[4][4];
#pragma unroll
  for (int mi = 0; mi < 4; ++mi)
#pragma unroll
    for (int ni = 0; ni < 4; ++ni) acc[mi][ni] = {0.f, 0.f, 0.f, 0.f};

  const int tb = t * 16;

  for (int kt = 0; kt < cH / BK; ++kt) {
    const int k0 = kt * BK;
    __syncthreads();
#pragma unroll
    for (int s = 0; s < 2; ++s) {
      const int ib = s * 4096 + tb;
      const int row = ib >> 6;
      const int cole = (ib & 63) >> 1;
      gload_lds16(Xb + (size_t)(m0 + row) * cH + k0 + cole,
                  ((char*)As) + s * 4096 + w * 1024);
      gload_lds16(W + (size_t)(n0 + row) * cH + k0 + cole,
                  ((char*)Bs) + s * 4096 + w * 1024);
    }
    asm volatile("s_waitcnt vmcnt(0)" ::: "memory");
    __syncthreads();

    short8 af[4], bfr[4];
#pragma unroll
    for (int mi = 0; mi < 4; ++mi)
      af[mi] = *reinterpret_cast<const short8*>(
          &As[(wm * 64 + mi * 16 + lr) * BK + lg * 8]);
#pragma unroll
    for (int ni = 0; ni < 4; ++ni)
      bfr[ni] = *reinterpret_cast<const short8*>(
          &Bs[(wn * 64 + ni * 16 + lr) * BK + lg * 8]);
#pragma unroll
    for (int mi = 0; mi < 4; ++mi)
#pragma unroll
      for (int ni = 0; ni < 4; ++ni)
        acc[mi][ni] = __builtin_amdgcn_mfma_f32_16x16x32_bf16(
            af[mi], bfr[ni], acc[mi][ni], 0, 0, 0);
  }

#pragma unroll
  for (int ni = 0; ni < 4; ++ni) {
    const int col = n0 + wn * 64 + ni * 16 + lr;
    const float bvv = bias[col];
#pragma unroll
    for (int mi = 0; mi < 4; ++mi) {
      const int row = m0 + wm * 64 + mi * 16 + lg * 4;
#pragma unroll
      for (int r = 0; r < 4; ++r)
        Out[(size_t)(row + r) * cH + col] =
            f2bf((acc[mi][ni][r] + bvv) * oscale);
    }
  }
}

// ---------------- Flash attention ----------------
// r21 (green, 126.8 us total): in-register P via swapped QK^T
// (mfma(kf,qf) -> lane holds P[k=n*16+lg*4+r][q=lr]); max-reduce via
// __shfl_xor(16/32); P-routing via swap32 + __shfl(idx) + select.
// V tr16 issued at top of iter; no P LDS tile. Block = 4 waves x 128 q-rows
// (r22's 2-wave split regressed: doubled per-head K/V staging traffic).
__global__ __launch_bounds__(256) void attn_kernel(
    const unsigned short* __restrict__ Qb,  // [B*S][H] bf16 (pre-scaled)
    const unsigned short* __restrict__ Kb,
    const unsigned short* __restrict__ Vb,
    const float* __restrict__ mask,         // [B][S]
    float* __restrict__ out) {              // [B*S][H] fp32
  __shared__ alignas(16) unsigned short Ks[2][64 * 64];  // 16 KB
  __shared__ alignas(16) unsigned short Vs[2][64 * 64];  // 16 KB

  const int qb = blockIdx.x;  // 0..15
  const int bh = blockIdx.y;  // 0..31
  const int b = bh >> 4, h = bh & 15;
  const int t = threadIdx.x;
  const int w = t >> 6, l = t & 63, lr = l & 15, lg = l >> 4;
  const int q0 = qb * 128 + w * 32;

  const unsigned short* Kbase = Kb + (size_t)b * cS * cH + h * cHD;
  const unsigned short* Vbase = Vb + (size_t)b * cS * cH + h * cHD;
  const float* mbase = mask + b * cS;

  // routing selectors (precomputed)
  const int sel = (l >> 4) & 1;       // 1 for lanes 16-31, 48-63
  const int idxm16 = l - 16;          // used by sel lanes
  const int idxp16 = (l + 16) & 63;   // used by !sel lanes

  // Staging decode (r7-verified).
  int rK[2], cK[2], rV[2], cV[2];
#pragma unroll
  for (int s2 = 0; s2 < 2; ++s2) {
    const int g = (w * 2 + s2) * 64 + l;
    const int gr = g >> 3, gc = g & 7;
    rK[s2] = gr;
    cK[s2] = (gc ^ (gr & 7)) * 8;
    rV[s2] = (gr >> 2) * 4 + (gc >> 1);
    cV[s2] = (gr & 3) * 16 + (gc & 1) * 8;
  }

  // Q fragments for 2 subtiles (q=lr rows; B-operand after swap)
  short8 qf[2][2];
#pragma unroll
  for (int qi = 0; qi < 2; ++qi) {
    const unsigned short* Qrow =
        Qb + (size_t)(b * cS + q0 + qi * 16 + lr) * cH + h * cHD;
    qf[qi][0] = *reinterpret_cast<const short8*>(Qrow + lg * 8);
    qf[qi][1] = *reinterpret_cast<const short8*>(Qrow + 32 + lg * 8);
  }

  short8 ones;
#pragma unroll
  for (int j = 0; j < 8; ++j) ones[j] = (short)0x3F80;

  f32x4 oacc[2][4];
  f32x4 osum[2];
  float mrow[2];  // per-lane running max for q = lr
#pragma unroll
  for (int qi = 0; qi < 2; ++qi) {
    osum[qi] = {0.f, 0.f, 0.f, 0.f};
#pragma unroll
    for (int d16 = 0; d16 < 4; ++d16) oacc[qi][d16] = {0.f, 0.f, 0.f, 0.f};
    mrow[qi] = -1e30f;
  }

  auto stage = [&](int bufi, int kv0) {
#pragma unroll
    for (int s2 = 0; s2 < 2; ++s2) {
      gload_lds16(Kbase + (size_t)(kv0 + rK[s2]) * cH + cK[s2],
                  (char*)&Ks[bufi][0] + (w * 2 + s2) * 1024);
      gload_lds16(Vbase + (size_t)(kv0 + rV[s2]) * cH + cV[s2],
                  (char*)&Vs[bufi][0] + (w * 2 + s2) * 1024);
    }
  };

  stage(0, 0);
  asm volatile("s_waitcnt vmcnt(0)" ::: "memory");
  __syncthreads();

  constexpr int NT = cS / 64;  // 32
  for (int kt = 0; kt < NT; ++kt) {
    const int bufi = kt & 1;
    if (kt + 1 < NT) stage(bufi ^ 1, (kt + 1) * 64);

    const unsigned short* Kt = &Ks[bufi][0];
    const unsigned short* Vt = &Vs[bufi][0];
    const int kv0 = kt * 64;

    // ---- load ALL K fragments (A-operand rows k=n*16+lr) ----
    short8 kfs[4][2];
#pragma unroll
    for (int n = 0; n < 4; ++n) {
      const int kr = n * 16 + lr;
      const unsigned sw = (unsigned)((kr & 7) << 4);
      const unsigned b0 = ((unsigned)(kr * 128 + lg * 16)) ^ sw;
      const unsigned b1 = ((unsigned)(kr * 128 + 64 + lg * 16)) ^ sw;
      kfs[n][0] = *reinterpret_cast<const short8*>((const char*)Kt + b0);
      kfs[n][1] = *reinterpret_cast<const short8*>((const char*)Kt + b1);
    }

    // ---- issue ALL V tr16 EARLY (latency hidden under QK^T+softmax) ----
    short4v tv[2][8];
#pragma unroll
    for (int ks2 = 0; ks2 < 2; ++ks2)
#pragma unroll
      for (int d16 = 0; d16 < 4; ++d16) {
        const unsigned short* a0 =
            Vt + (ks2 * 8 + lg * 2) * 256 + d16 * 64 + lr * 4;
        tv[ks2][2 * d16] = tr16(a0);
        tv[ks2][2 * d16 + 1] = tr16(a0 + 256);
      }

    // ---- mask (k = n*16 + lg*4 + r), log2e-scaled ----
    f32x4 maskv[4];
#pragma unroll
    for (int n = 0; n < 4; ++n) {
      f32x4 m = *reinterpret_cast<const f32x4*>(&mbase[kv0 + n * 16 + lg * 4]);
#pragma unroll
      for (int r = 0; r < 4; ++r) m[r] *= LOG2E;
      maskv[n] = m;
    }

    // ---- swapped QK^T: sc[qi][n][r] = S[k=n*16+lg*4+r][q=lr] + mask[k] ----
    f32x4 sc[2][4];
#pragma unroll
    for (int n = 0; n < 4; ++n)
#pragma unroll
      for (int qi = 0; qi < 2; ++qi) {
        f32x4 z = {0.f, 0.f, 0.f, 0.f};
        z = __builtin_amdgcn_mfma_f32_16x16x32_bf16(kfs[n][0], qf[qi][0], z, 0, 0, 0);
        z = __builtin_amdgcn_mfma_f32_16x16x32_bf16(kfs[n][1], qf[qi][1], z, 0, 0, 0);
        sc[qi][n] = z + maskv[n];
      }

    // ---- softmax max: local 16-tree + shfl_xor(16,32) cross-lg reduce ----
    float mnew[2];
    int ok = 1;
#pragma unroll
    for (int qi = 0; qi < 2; ++qi) {
      float a0 = fmaxf(fmaxf(sc[qi][0][0], sc[qi][0][1]),
                       fmaxf(sc[qi][0][2], sc[qi][0][3]));
      float a1 = fmaxf(fmaxf(sc[qi][1][0], sc[qi][1][1]),
                       fmaxf(sc[qi][1][2], sc[qi][1][3]));
      float a2 = fmaxf(fmaxf(sc[qi][2][0], sc[qi][2][1]),
                       fmaxf(sc[qi][2][2], sc[qi][2][3]));
      float a3 = fmaxf(fmaxf(sc[qi][3][0], sc[qi][3][1]),
                       fmaxf(sc[qi][3][2], sc[qi][3][3]));
      float mx = fmaxf(fmaxf(a0, a1), fmaxf(a2, a3));
      mx = fmaxf(mx, __shfl_xor(mx, 16));
      mx = fmaxf(mx, __shfl_xor(mx, 32));
      mnew[qi] = fmaxf(mrow[qi], mx);
      ok &= (mx - mrow[qi] <= 11.5416f) ? 1 : 0;
    }
    if (!__all(ok)) {
#pragma unroll
      for (int qi = 0; qi < 2; ++qi) {
        const float dlt = mrow[qi] - mnew[qi];  // <= 0, per q=lr
        mrow[qi] = mnew[qi];
#pragma unroll
        for (int r = 0; r < 4; ++r) {
          // oacc/osum row r is q = lg*4+r -> delta from lane (lg*4+r)
          const float s = fexp2(__shfl(dlt, lg * 4 + r));
          osum[qi][r] *= s;
#pragma unroll
          for (int d16 = 0; d16 < 4; ++d16) oacc[qi][d16][r] *= s;
        }
      }
    }

    // ---- P = exp2(sc - mrow), bf16-pack into dwords per block n ----
    unsigned d0[2][4], d1[2][4];
#pragma unroll
    for (int qi = 0; qi < 2; ++qi)
#pragma unroll
      for (int n = 0; n < 4; ++n) {
        const float p0 = fexp2(sc[qi][n][0] - mrow[qi]);
        const float p1 = fexp2(sc[qi][n][1] - mrow[qi]);
        const float p2 = fexp2(sc[qi][n][2] - mrow[qi]);
        const float p3 = fexp2(sc[qi][n][3] - mrow[qi]);
        d0[qi][n] = (unsigned)f2bf(p0) | ((unsigned)f2bf(p1) << 16);
        d1[qi][n] = (unsigned)f2bf(p2) | ((unsigned)f2bf(p3) << 16);
      }

    // ---- drain V reads; PV with swap32+shfl routed pa ----
    asm volatile("s_waitcnt lgkmcnt(0)" ::: "memory");
    __builtin_amdgcn_sched_barrier(0);
#pragma unroll
    for (int ks2 = 0; ks2 < 2; ++ks2) {
      const int a = ks2 * 2;
      short8 pa[2];
#pragma unroll
      for (int qi = 0; qi < 2; ++qi) {
        unsigned A0 = d0[qi][a], B0 = d0[qi][a + 1];
        unsigned A1 = d1[qi][a], B1 = d1[qi][a + 1];
        swap32(A0, B0);  // A0=[X0-31|Y0-31], B0=[X32-63|Y32-63]
        swap32(A1, B1);
        const unsigned sB0 = (unsigned)__shfl((int)B0, idxm16);
        const unsigned sA0 = (unsigned)__shfl((int)A0, idxp16);
        const unsigned sB1 = (unsigned)__shfl((int)B1, idxm16);
        const unsigned sA1 = (unsigned)__shfl((int)A1, idxp16);
        const unsigned j01 = sel ? sB0 : A0;
        const unsigned j45 = sel ? B0 : sA0;
        const unsigned j23 = sel ? sB1 : A1;
        const unsigned j67 = sel ? B1 : sA1;
        uint4v q4 = {j01, j23, j45, j67};
        pa[qi] = __builtin_bit_cast(short8, q4);
      }
      osum[0] = __builtin_amdgcn_mfma_f32_16x16x32_bf16(pa[0], ones, osum[0],
                                                        0, 0, 0);
      osum[1] = __builtin_amdgcn_mfma_f32_16x16x32_bf16(pa[1], ones, osum[1],
                                                        0, 0, 0);
#pragma unroll
      for (int d16 = 0; d16 < 4; ++d16) {
        short8 vf;
#pragma unroll
        for (int j = 0; j < 4; ++j) {
          vf[j] = tv[ks2][2 * d16][j];
          vf[4 + j] = tv[ks2][2 * d16 + 1][j];
        }
        oacc[0][d16] = __builtin_amdgcn_mfma_f32_16x16x32_bf16(
            pa[0], vf, oacc[0][d16], 0, 0, 0);
        oacc[1][d16] = __builtin_amdgcn_mfma_f32_16x16x32_bf16(
            pa[1], vf, oacc[1][d16], 0, 0, 0);
      }
    }

    asm volatile("s_waitcnt vmcnt(0)" ::: "memory");
    __syncthreads();  // staged tile kt+1 ready; all waves done with buf kt
  }

  // fp32 store; denominator from the MFMA row-sum accumulator
#pragma unroll
  for (int qi = 0; qi < 2; ++qi) {
    float* obase =
        out + (size_t)(b * cS + q0 + qi * 16 + lg * 4) * cH + h * cHD;
#pragma unroll
    for (int r = 0; r < 4; ++r) {
      const float inv = 1.0f / osum[qi][r];
#pragma unroll
      for (int d16 = 0; d16 < 4; ++d16)
        obase[(size_t)r * cH + d16 * 16 + lr] = oacc[qi][d16][r] * inv;
    }
  }
}

// ---------------- launcher ----------------
extern "C" void kernel_launch(void* const* d_in, const int* in_sizes, int n_in,
                              void* d_out, int out_size, void* d_ws,
                              size_t ws_size, hipStream_t stream) {
  const float* X = (const float*)d_in[0];     // [B,S,H]
  const float* mask = (const float*)d_in[1];  // [B,1,1,S]
  const float* Wq = (const float*)d_in[2];
  const float* bq = (const float*)d_in[3];
  const float* Wk = (const float*)d_in[4];
  const float* bk = (const float*)d_in[5];
  const float* Wv = (const float*)d_in[6];
  const float* bv = (const float*)d_in[7];
  float* outp = (float*)d_out;  // fp32 (reference output dtype)

  // workspace (38 MB; established safe):
  char* ws = (char*)d_ws;
  const size_t MB = 1 << 20;
  unsigned short* Xb  = (unsigned short*)(ws + 0 * MB);   // 8 MB
  unsigned short* Wqb = (unsigned short*)(ws + 8 * MB);   // 2 MB
  unsigned short* Wkb = (unsigned short*)(ws + 10 * MB);  // 2 MB
  unsigned short* Wvb = (unsigned short*)(ws + 12 * MB);  // 2 MB
  unsigned short* Qb  = (unsigned short*)(ws + 14 * MB);  // 8 MB
  unsigned short* Kb  = (unsigned short*)(ws + 22 * MB);  // 8 MB
  unsigned short* Vb  = (unsigned short*)(ws + 30 * MB);  // 8 MB

  cvt_f32_bf16<<<cBS * cH / 1024, 256, 0, stream>>>(X, Xb, cBS * cH);
  cvt_f32_bf16<<<cH * cH / 1024, 256, 0, stream>>>(Wq, Wqb, cH * cH);
  cvt_f32_bf16<<<cH * cH / 1024, 256, 0, stream>>>(Wk, Wkb, cH * cH);
  cvt_f32_bf16<<<cH * cH / 1024, 256, 0, stream>>>(Wv, Wvb, cH * cH);

  qkv_gemm<<<dim3(24, 32), 256, 0, stream>>>(Xb, Wqb, Wkb, Wvb, bq, bk, bv,
                                             Qb, Kb, Vb);
  attn_kernel<<<dim3(16, 32), 256, 0, stream>>>(Qb, Kb, Vb, mask, outp);
}

// Round 24
// 126.173 us; speedup vs baseline: 1.0588x; 1.0034x over previous
//
#include <hip/hip_runtime.h>
#include <hip/hip_bf16.h>
#include <stdint.h>

// Problem constants
constexpr int cB = 2;
constexpr int cS = 2048;
constexpr int cH = 1024;
constexpr int cNH = 16;
constexpr int cHD = 64;
constexpr int cBS = cB * cS;  // 4096

typedef short short8 __attribute__((ext_vector_type(8)));
typedef short short4v __attribute__((ext_vector_type(4)));
typedef float f32x4 __attribute__((ext_vector_type(4)));
typedef unsigned short us4 __attribute__((ext_vector_type(4)));
typedef unsigned uint4v __attribute__((ext_vector_type(4)));

constexpr float LOG2E = 1.4426950408889634f;

// HW bf16 convert (RNE)
__device__ inline unsigned short f2bf(float f) {
  __hip_bfloat16 h = __float2bfloat16(f);
  return __builtin_bit_cast(unsigned short, h);
}

// Bare v_exp_f32 (2^x) — r17-verified.
__device__ inline float fexp2(float x) {
#if __has_builtin(__builtin_amdgcn_exp2f)
  return __builtin_amdgcn_exp2f(x);
#else
  return __expf(x * 0.6931471805599453f);
#endif
}

__device__ inline void gload_lds16(const void* g, void* l) {
  __builtin_amdgcn_global_load_lds(
      (const __attribute__((address_space(1))) void*)g,
      (__attribute__((address_space(3))) void*)l,
      16, 0, 0);
}

// ds_read_b64_tr_b16 (verified r7)
__device__ inline short4v tr16(const unsigned short* p) {
  short4v d;
  auto p3 = (const __attribute__((address_space(3))) unsigned short*)p;
  asm volatile("ds_read_b64_tr_b16 %0, %1" : "=v"(d) : "v"(p3) : "memory");
  return d;
}

// permlane32 swap (r21-verified in-kernel): a' = [a(0-31)|b(0-31)],
// b' = [a(32-63)|b(32-63)].
__device__ inline void swap32(unsigned& a, unsigned& b) {
  asm("v_permlane32_swap_b32 %0, %1" : "+v"(a), "+v"(b));
}

// ---------------- fp32 -> bf16 convert ----------------
__global__ void cvt_f32_bf16(const float* __restrict__ src,
                             unsigned short* __restrict__ dst, int n) {
  int i = (blockIdx.x * blockDim.x + threadIdx.x) * 4;
  if (i >= n) return;
  f32x4 v = *reinterpret_cast<const f32x4*>(src + i);
  us4 o = {f2bf(v[0]), f2bf(v[1]), f2bf(v[2]), f2bf(v[3])};
  *reinterpret_cast<us4*>(dst + i) = o;
}

// ---------------- QKV GEMM (r17/r20, green) ----------------
constexpr int BM = 128, BN = 128, BK = 32;

__global__ __launch_bounds__(256) void qkv_gemm(
    const unsigned short* __restrict__ Xb,  // [4096][1024] bf16
    const unsigned short* __restrict__ Wqb, // [1024][1024] bf16
    const unsigned short* __restrict__ Wkb,
    const unsigned short* __restrict__ Wvb,
    const float* __restrict__ bq, const float* __restrict__ bk,
    const float* __restrict__ bv,
    unsigned short* __restrict__ Qb, unsigned short* __restrict__ Kb,
    unsigned short* __restrict__ Vb) {
  __shared__ alignas(16) unsigned short As[BM * BK];  // 8 KB
  __shared__ alignas(16) unsigned short Bs[BN * BK];

  const int nb = blockIdx.x;  // 0..23
  const int mb = blockIdx.y;  // 0..31
  const int m0 = mb * BM;
  const int wsel = nb >> 3;
  const int n0 = (nb & 7) * BN;
  const unsigned short* W = (wsel == 0) ? Wqb : (wsel == 1 ? Wkb : Wvb);
  const float* bias = (wsel == 0) ? bq : (wsel == 1 ? bk : bv);
  unsigned short* Out = (wsel == 0) ? Qb : (wsel == 1 ? Kb : Vb);
  const float oscale = (wsel == 0) ? 0.125f * LOG2E : 1.0f;

  const int t = threadIdx.x;
  const int w = t >> 6, l = t & 63, lr = l & 15, lg = l >> 4;
  const int wm = w >> 1, wn = w & 1;

  f32x4 acc[4][4];
#pragma unroll
  for (int mi = 0; mi < 4; ++mi)
#pragma unroll
    for (int ni = 0; ni < 4; ++ni) acc[mi][ni] = {0.f, 0.f, 0.f, 0.f};

  const int tb = t * 16;

  for (int kt = 0; kt < cH / BK; ++kt) {
    const int k0 = kt * BK;
    __syncthreads();
#pragma unroll
    for (int s = 0; s < 2; ++s) {
      const int ib = s * 4096 + tb;
      const int row = ib >> 6;
      const int cole = (ib & 63) >> 1;
      gload_lds16(Xb + (size_t)(m0 + row) * cH + k0 + cole,
                  ((char*)As) + s * 4096 + w * 1024);
      gload_lds16(W + (size_t)(n0 + row) * cH + k0 + cole,
                  ((char*)Bs) + s * 4096 + w * 1024);
    }
    asm volatile("s_waitcnt vmcnt(0)" ::: "memory");
    __syncthreads();

    short8 af[4], bfr[4];
#pragma unroll
    for (int mi = 0; mi < 4; ++mi)
      af[mi] = *reinterpret_cast<const short8*>(
          &As[(wm * 64 + mi * 16 + lr) * BK + lg * 8]);
#pragma unroll
    for (int ni = 0; ni < 4; ++ni)
      bfr[ni] = *reinterpret_cast<const short8*>(
          &Bs[(wn * 64 + ni * 16 + lr) * BK + lg * 8]);
#pragma unroll
    for (int mi = 0; mi < 4; ++mi)
#pragma unroll
      for (int ni = 0; ni < 4; ++ni)
        acc[mi][ni] = __builtin_amdgcn_mfma_f32_16x16x32_bf16(
            af[mi], bfr[ni], acc[mi][ni], 0, 0, 0);
  }

#pragma unroll
  for (int ni = 0; ni < 4; ++ni) {
    const int col = n0 + wn * 64 + ni * 16 + lr;
    const float bvv = bias[col];
#pragma unroll
    for (int mi = 0; mi < 4; ++mi) {
      const int row = m0 + wm * 64 + mi * 16 + lg * 4;
#pragma unroll
      for (int r = 0; r < 4; ++r)
        Out[(size_t)(row + r) * cH + col] =
            f2bf((acc[mi][ni][r] + bvv) * oscale);
    }
  }
}

// ---------------- Flash attention ----------------
// r21/r23 (green): in-register P via swapped QK^T; max via __shfl_xor(16/32);
// P-routing via swap32 + __shfl + select; V tr16 at top of iter.
// r24: s_setprio(1) around the pure-reg PV MFMA cluster (T5; regime = 2
// independent barrier-groups/CU give phase diversity to arbitrate).
__global__ __launch_bounds__(256) void attn_kernel(
    const unsigned short* __restrict__ Qb,  // [B*S][H] bf16 (pre-scaled)
    const unsigned short* __restrict__ Kb,
    const unsigned short* __restrict__ Vb,
    const float* __restrict__ mask,         // [B][S]
    float* __restrict__ out) {              // [B*S][H] fp32
  __shared__ alignas(16) unsigned short Ks[2][64 * 64];  // 16 KB
  __shared__ alignas(16) unsigned short Vs[2][64 * 64];  // 16 KB

  const int qb = blockIdx.x;  // 0..15
  const int bh = blockIdx.y;  // 0..31
  const int b = bh >> 4, h = bh & 15;
  const int t = threadIdx.x;
  const int w = t >> 6, l = t & 63, lr = l & 15, lg = l >> 4;
  const int q0 = qb * 128 + w * 32;

  const unsigned short* Kbase = Kb + (size_t)b * cS * cH + h * cHD;
  const unsigned short* Vbase = Vb + (size_t)b * cS * cH + h * cHD;
  const float* mbase = mask + b * cS;

  // routing selectors (precomputed)
  const int sel = (l >> 4) & 1;       // 1 for lanes 16-31, 48-63
  const int idxm16 = l - 16;          // used by sel lanes
  const int idxp16 = (l + 16) & 63;   // used by !sel lanes

  // Staging decode (r7-verified).
  int rK[2], cK[2], rV[2], cV[2];
#pragma unroll
  for (int s2 = 0; s2 < 2; ++s2) {
    const int g = (w * 2 + s2) * 64 + l;
    const int gr = g >> 3, gc = g & 7;
    rK[s2] = gr;
    cK[s2] = (gc ^ (gr & 7)) * 8;
    rV[s2] = (gr >> 2) * 4 + (gc >> 1);
    cV[s2] = (gr & 3) * 16 + (gc & 1) * 8;
  }

  // Q fragments for 2 subtiles (q=lr rows; B-operand after swap)
  short8 qf[2][2];
#pragma unroll
  for (int qi = 0; qi < 2; ++qi) {
    const unsigned short* Qrow =
        Qb + (size_t)(b * cS + q0 + qi * 16 + lr) * cH + h * cHD;
    qf[qi][0] = *reinterpret_cast<const short8*>(Qrow + lg * 8);
    qf[qi][1] = *reinterpret_cast<const short8*>(Qrow + 32 + lg * 8);
  }

  short8 ones;
#pragma unroll
  for (int j = 0; j < 8; ++j) ones[j] = (short)0x3F80;

  f32x4 oacc[2][4];
  f32x4 osum[2];
  float mrow[2];  // per-lane running max for q = lr
#pragma unroll
  for (int qi = 0; qi < 2; ++qi) {
    osum[qi] = {0.f, 0.f, 0.f, 0.f};
#pragma unroll
    for (int d16 = 0; d16 < 4; ++d16) oacc[qi][d16] = {0.f, 0.f, 0.f, 0.f};
    mrow[qi] = -1e30f;
  }

  auto stage = [&](int bufi, int kv0) {
#pragma unroll
    for (int s2 = 0; s2 < 2; ++s2) {
      gload_lds16(Kbase + (size_t)(kv0 + rK[s2]) * cH + cK[s2],
                  (char*)&Ks[bufi][0] + (w * 2 + s2) * 1024);
      gload_lds16(Vbase + (size_t)(kv0 + rV[s2]) * cH + cV[s2],
                  (char*)&Vs[bufi][0] + (w * 2 + s2) * 1024);
    }
  };

  stage(0, 0);
  asm volatile("s_waitcnt vmcnt(0)" ::: "memory");
  __syncthreads();

  constexpr int NT = cS / 64;  // 32
  for (int kt = 0; kt < NT; ++kt) {
    const int bufi = kt & 1;
    if (kt + 1 < NT) stage(bufi ^ 1, (kt + 1) * 64);

    const unsigned short* Kt = &Ks[bufi][0];
    const unsigned short* Vt = &Vs[bufi][0];
    const int kv0 = kt * 64;

    // ---- load ALL K fragments (A-operand rows k=n*16+lr) ----
    short8 kfs[4][2];
#pragma unroll
    for (int n = 0; n < 4; ++n) {
      const int kr = n * 16 + lr;
      const unsigned sw = (unsigned)((kr & 7) << 4);
      const unsigned b0 = ((unsigned)(kr * 128 + lg * 16)) ^ sw;
      const unsigned b1 = ((unsigned)(kr * 128 + 64 + lg * 16)) ^ sw;
      kfs[n][0] = *reinterpret_cast<const short8*>((const char*)Kt + b0);
      kfs[n][1] = *reinterpret_cast<const short8*>((const char*)Kt + b1);
    }

    // ---- issue ALL V tr16 EARLY (latency hidden under QK^T+softmax) ----
    short4v tv[2][8];
#pragma unroll
    for (int ks2 = 0; ks2 < 2; ++ks2)
#pragma unroll
      for (int d16 = 0; d16 < 4; ++d16) {
        const unsigned short* a0 =
            Vt + (ks2 * 8 + lg * 2) * 256 + d16 * 64 + lr * 4;
        tv[ks2][2 * d16] = tr16(a0);
        tv[ks2][2 * d16 + 1] = tr16(a0 + 256);
      }

    // ---- mask (k = n*16 + lg*4 + r), log2e-scaled ----
    f32x4 maskv[4];
#pragma unroll
    for (int n = 0; n < 4; ++n) {
      f32x4 m = *reinterpret_cast<const f32x4*>(&mbase[kv0 + n * 16 + lg * 4]);
#pragma unroll
      for (int r = 0; r < 4; ++r) m[r] *= LOG2E;
      maskv[n] = m;
    }

    // ---- swapped QK^T: sc[qi][n][r] = S[k=n*16+lg*4+r][q=lr] + mask[k] ----
    f32x4 sc[2][4];
#pragma unroll
    for (int n = 0; n < 4; ++n)
#pragma unroll
      for (int qi = 0; qi < 2; ++qi) {
        f32x4 z = {0.f, 0.f, 0.f, 0.f};
        z = __builtin_amdgcn_mfma_f32_16x16x32_bf16(kfs[n][0], qf[qi][0], z, 0, 0, 0);
        z = __builtin_amdgcn_mfma_f32_16x16x32_bf16(kfs[n][1], qf[qi][1], z, 0, 0, 0);
        sc[qi][n] = z + maskv[n];
      }

    // ---- softmax max: local 16-tree + shfl_xor(16,32) cross-lg reduce ----
    float mnew[2];
    int ok = 1;
#pragma unroll
    for (int qi = 0; qi < 2; ++qi) {
      float a0 = fmaxf(fmaxf(sc[qi][0][0], sc[qi][0][1]),
                       fmaxf(sc[qi][0][2], sc[qi][0][3]));
      float a1 = fmaxf(fmaxf(sc[qi][1][0], sc[qi][1][1]),
                       fmaxf(sc[qi][1][2], sc[qi][1][3]));
      float a2 = fmaxf(fmaxf(sc[qi][2][0], sc[qi][2][1]),
                       fmaxf(sc[qi][2][2], sc[qi][2][3]));
      float a3 = fmaxf(fmaxf(sc[qi][3][0], sc[qi][3][1]),
                       fmaxf(sc[qi][3][2], sc[qi][3][3]));
      float mx = fmaxf(fmaxf(a0, a1), fmaxf(a2, a3));
      mx = fmaxf(mx, __shfl_xor(mx, 16));
      mx = fmaxf(mx, __shfl_xor(mx, 32));
      mnew[qi] = fmaxf(mrow[qi], mx);
      ok &= (mx - mrow[qi] <= 11.5416f) ? 1 : 0;
    }
    if (!__all(ok)) {
#pragma unroll
      for (int qi = 0; qi < 2; ++qi) {
        const float dlt = mrow[qi] - mnew[qi];  // <= 0, per q=lr
        mrow[qi] = mnew[qi];
#pragma unroll
        for (int r = 0; r < 4; ++r) {
          // oacc/osum row r is q = lg*4+r -> delta from lane (lg*4+r)
          const float s = fexp2(__shfl(dlt, lg * 4 + r));
          osum[qi][r] *= s;
#pragma unroll
          for (int d16 = 0; d16 < 4; ++d16) oacc[qi][d16][r] *= s;
        }
      }
    }

    // ---- P = exp2(sc - mrow), bf16-pack into dwords per block n ----
    unsigned d0[2][4], d1[2][4];
#pragma unroll
    for (int qi = 0; qi < 2; ++qi)
#pragma unroll
      for (int n = 0; n < 4; ++n) {
        const float p0 = fexp2(sc[qi][n][0] - mrow[qi]);
        const float p1 = fexp2(sc[qi][n][1] - mrow[qi]);
        const float p2 = fexp2(sc[qi][n][2] - mrow[qi]);
        const float p3 = fexp2(sc[qi][n][3] - mrow[qi]);
        d0[qi][n] = (unsigned)f2bf(p0) | ((unsigned)f2bf(p1) << 16);
        d1[qi][n] = (unsigned)f2bf(p2) | ((unsigned)f2bf(p3) << 16);
      }

    // ---- drain V reads; PV with swap32+shfl routed pa ----
    asm volatile("s_waitcnt lgkmcnt(0)" ::: "memory");
    __builtin_amdgcn_sched_barrier(0);
#pragma unroll
    for (int ks2 = 0; ks2 < 2; ++ks2) {
      const int a = ks2 * 2;
      short8 pa[2];
#pragma unroll
      for (int qi = 0; qi < 2; ++qi) {
        unsigned A0 = d0[qi][a], B0 = d0[qi][a + 1];
        unsigned A1 = d1[qi][a], B1 = d1[qi][a + 1];
        swap32(A0, B0);  // A0=[X0-31|Y0-31], B0=[X32-63|Y32-63]
        swap32(A1, B1);
        const unsigned sB0 = (unsigned)__shfl((int)B0, idxm16);
        const unsigned sA0 = (unsigned)__shfl((int)A0, idxp16);
        const unsigned sB1 = (unsigned)__shfl((int)B1, idxm16);
        const unsigned sA1 = (unsigned)__shfl((int)A1, idxp16);
        const unsigned j01 = sel ? sB0 : A0;
        const unsigned j45 = sel ? B0 : sA0;
        const unsigned j23 = sel ? sB1 : A1;
        const unsigned j67 = sel ? B1 : sA1;
        uint4v q4 = {j01, j23, j45, j67};
        pa[qi] = __builtin_bit_cast(short8, q4);
      }
      // T5: pure-reg MFMA cluster — raise wave priority so MFMA-phase waves
      // win issue arbitration against the other block's VALU-phase waves.
      __builtin_amdgcn_s_setprio(1);
      osum[0] = __builtin_amdgcn_mfma_f32_16x16x32_bf16(pa[0], ones, osum[0],
                                                        0, 0, 0);
      osum[1] = __builtin_amdgcn_mfma_f32_16x16x32_bf16(pa[1], ones, osum[1],
                                                        0, 0, 0);
#pragma unroll
      for (int d16 = 0; d16 < 4; ++d16) {
        short8 vf;
#pragma unroll
        for (int j = 0; j < 4; ++j) {
          vf[j] = tv[ks2][2 * d16][j];
          vf[4 + j] = tv[ks2][2 * d16 + 1][j];
        }
        oacc[0][d16] = __builtin_amdgcn_mfma_f32_16x16x32_bf16(
            pa[0], vf, oacc[0][d16], 0, 0, 0);
        oacc[1][d16] = __builtin_amdgcn_mfma_f32_16x16x32_bf16(
            pa[1], vf, oacc[1][d16], 0, 0, 0);
      }
      __builtin_amdgcn_s_setprio(0);
    }

    asm volatile("s_waitcnt vmcnt(0)" ::: "memory");
    __syncthreads();  // staged tile kt+1 ready; all waves done with buf kt
  }

  // fp32 store; denominator from the MFMA row-sum accumulator
#pragma unroll
  for (int qi = 0; qi < 2; ++qi) {
    float* obase =
        out + (size_t)(b * cS + q0 + qi * 16 + lg * 4) * cH + h * cHD;
#pragma unroll
    for (int r = 0; r < 4; ++r) {
      const float inv = 1.0f / osum[qi][r];
#pragma unroll
      for (int d16 = 0; d16 < 4; ++d16)
        obase[(size_t)r * cH + d16 * 16 + lr] = oacc[qi][d16][r] * inv;
    }
  }
}

// ---------------- launcher ----------------
extern "C" void kernel_launch(void* const* d_in, const int* in_sizes, int n_in,
                              void* d_out, int out_size, void* d_ws,
                              size_t ws_size, hipStream_t stream) {
  const float* X = (const float*)d_in[0];     // [B,S,H]
  const float* mask = (const float*)d_in[1];  // [B,1,1,S]
  const float* Wq = (const float*)d_in[2];
  const float* bq = (const float*)d_in[3];
  const float* Wk = (const float*)d_in[4];
  const float* bk = (const float*)d_in[5];
  const float* Wv = (const float*)d_in[6];
  const float* bv = (const float*)d_in[7];
  float* outp = (float*)d_out;  // fp32 (reference output dtype)

  // workspace (38 MB; established safe):
  char* ws = (char*)d_ws;
  const size_t MB = 1 << 20;
  unsigned short* Xb  = (unsigned short*)(ws + 0 * MB);   // 8 MB
  unsigned short* Wqb = (unsigned short*)(ws + 8 * MB);   // 2 MB
  unsigned short* Wkb = (unsigned short*)(ws + 10 * MB);  // 2 MB
  unsigned short* Wvb = (unsigned short*)(ws + 12 * MB);  // 2 MB
  unsigned short* Qb  = (unsigned short*)(ws + 14 * MB);  // 8 MB
  unsigned short* Kb  = (unsigned short*)(ws + 22 * MB);  // 8 MB
  unsigned short* Vb  = (unsigned short*)(ws + 30 * MB);  // 8 MB

  cvt_f32_bf16<<<cBS * cH / 1024, 256, 0, stream>>>(X, Xb, cBS * cH);
  cvt_f32_bf16<<<cH * cH / 1024, 256, 0, stream>>>(Wq, Wqb, cH * cH);
  cvt_f32_bf16<<<cH * cH / 1024, 256, 0, stream>>>(Wk, Wkb, cH * cH);
  cvt_f32_bf16<<<cH * cH / 1024, 256, 0, stream>>>(Wv, Wvb, cH * cH);

  qkv_gemm<<<dim3(24, 32), 256, 0, stream>>>(Xb, Wqb, Wkb, Wvb, bq, bk, bv,
                                             Qb, Kb, Vb);
  attn_kernel<<<dim3(16, 32), 256, 0, stream>>>(Qb, Kb, Vb, mask, outp);
}